// Round 1
// 681.279 us; speedup vs baseline: 1.0686x; 1.0686x over previous
//
#include <hip/hip_runtime.h>
#include <math.h>

// N=500000, F=H=128, S=256.
// out = tanh( mlp_l(x) + pooled[seg] ), pooled = segment_mean( mlp_g(x) )
// fp16 MFMA (16x16x32_f16), single-precision-operand (no hi/lo split):
//   error ~2^-11 rel on x, W, h vs bf16 W-rounding 2^-8 before -> absmax ~0.003.
// Two passes: gamma (pooled via in-register segmented reduction + atomics),
// lambda (+pooled +biases +tanh, direct store). One barrier per pass.

#define FW 128
#define SEGS 256
#define TILE_R 64
#define XSTR 136   // halfs per LDS row: 272 B (16B-aligned rows; dword stride 68 = 4 mod 32)

typedef __attribute__((ext_vector_type(8))) _Float16 f16x8;
typedef __attribute__((ext_vector_type(4))) _Float16 f16x4;
typedef __attribute__((ext_vector_type(4))) float f32x4;

__device__ __forceinline__ float fast_tanh(float x) {
    float ax = fabsf(x);
    float t = __expf(-2.0f * ax);                // exp2-based, ~1e-6 rel err
    float r = (1.0f - t) / (1.0f + t);
    return __builtin_copysignf(r, x);
}

// --- prep: blocks 0-3 pack W fp32 -> fp16 B-fragments; block 4: inv_counts + zero pooled ---
// frag f = nt*4 + ks; lane l; P[f*64+l] = 8 fp16: W[ks*32 + (l>>4)*8 + j][nt*16 + (l&15)]
__global__ void prep_kernel(const float* __restrict__ W0, const float* __restrict__ W1,
                            const float* __restrict__ W2, const float* __restrict__ W3,
                            uint4* __restrict__ P0, uint4* __restrict__ P1,
                            uint4* __restrict__ P2, uint4* __restrict__ P3,
                            const int* __restrict__ seg, float* __restrict__ inv_counts,
                            float* __restrict__ pooled, int N)
{
    if (blockIdx.x == 4) {
        int s = threadIdx.x;
        float4* p4 = (float4*)pooled;
        for (int i = s; i < SEGS * FW / 4; i += 256) p4[i] = make_float4(0.f, 0.f, 0.f, 0.f);
        // per-segment count via binary search over sorted segment_ids
        int lo0 = 0, hi0 = N;
        while (lo0 < hi0) { int mid = (lo0 + hi0) >> 1; if (seg[mid] < s) lo0 = mid + 1; else hi0 = mid; }
        int lo1 = lo0, hi1 = N;
        while (lo1 < hi1) { int mid = (lo1 + hi1) >> 1; if (seg[mid] < s + 1) lo1 = mid + 1; else hi1 = mid; }
        int c = lo1 - lo0;
        inv_counts[s] = 1.0f / (float)(c > 0 ? c : 1);
        return;
    }
    const float* W = blockIdx.x == 0 ? W0 : blockIdx.x == 1 ? W1 : blockIdx.x == 2 ? W2 : W3;
    uint4*       P = blockIdx.x == 0 ? P0 : blockIdx.x == 1 ? P1 : blockIdx.x == 2 ? P2 : P3;
    for (int s = threadIdx.x; s < 32 * 64; s += 256) {
        int f = s >> 6, l = s & 63;
        int nt = f >> 2, ks = f & 3;
        int n = nt * 16 + (l & 15);
        int k0 = ks * 32 + ((l >> 4) << 3);
        union { _Float16 h[8]; uint4 q; } u;
        #pragma unroll
        for (int j = 0; j < 8; ++j) u.h[j] = (_Float16)W[(k0 + j) * FW + n];
        P[s] = u.q;
    }
}

// --- stage x tile: fp32 -> fp16 in LDS (coalesced float4 reads, 8B LDS writes) ---
__device__ __forceinline__ void stage_x(_Float16* A, const float* __restrict__ x, int r0, int N) {
    const float4* x4 = (const float4*)x;
    for (int j = threadIdx.x; j < TILE_R * 32; j += 256) {
        int row = j >> 5, c4 = j & 31;
        float4 v = make_float4(0.f, 0.f, 0.f, 0.f);
        if (r0 + row < N) v = x4[(long)r0 * 32 + j];
        f16x4 h;
        h.x = (_Float16)v.x; h.y = (_Float16)v.y; h.z = (_Float16)v.z; h.w = (_Float16)v.w;
        *(f16x4*)&A[row * XSTR + c4 * 4] = h;
    }
}

__device__ __forceinline__ void mfma_layer(const _Float16* A, const uint4* __restrict__ Wp,
                                           int abase, int lane, f32x4 acc[8])
{
    #pragma unroll
    for (int nt = 0; nt < 8; ++nt) acc[nt] = (f32x4){0.f, 0.f, 0.f, 0.f};
    #pragma unroll
    for (int ks = 0; ks < 4; ++ks) {
        f16x8 a = *(const f16x8*)&A[abase + ks * 32];
        #pragma unroll
        for (int nt = 0; nt < 8; ++nt) {
            f16x8 b = __builtin_bit_cast(f16x8, Wp[(nt * 4 + ks) * 64 + lane]);
            acc[nt] = __builtin_amdgcn_mfma_f32_16x16x32_f16(a, b, acc[nt], 0, 0, 0);
        }
    }
}

// --- two-layer MLP core. All A rows touched after staging are wave-private
// (L1 reads rows wv*16+l15; h overwrite writes rows wv*16+q*4+r; L2 reads same),
// so no __syncthreads needed here — only intra-wave DS ordering. ---
__device__ __forceinline__ void mlp_core(_Float16* A,
    const uint4* __restrict__ Wp1, const float* __restrict__ b1,
    const uint4* __restrict__ Wp2,
    int wv, int lane, f32x4 acc2[8])
{
    int l15 = lane & 15, q = lane >> 4;
    int abase = (wv * 16 + l15) * XSTR + q * 8;   // halfs

    f32x4 acc1[8];
    mfma_layer(A, Wp1, abase, lane, acc1);

    // h = relu(acc1 + b1) -> fp16, in-place (writes depend on all L1 reads via acc1)
    #pragma unroll
    for (int nt = 0; nt < 8; ++nt) {
        float bias = b1[nt * 16 + l15];
        #pragma unroll
        for (int r = 0; r < 4; ++r) {
            int row = wv * 16 + q * 4 + r;
            A[row * XSTR + nt * 16 + l15] = (_Float16)fmaxf(acc1[nt][r] + bias, 0.f);
        }
    }
    // intra-wave RAW on h: drain own ds_writes; sched_barrier pins (rule-18 pattern)
    asm volatile("s_waitcnt lgkmcnt(0)" ::: "memory");
    __builtin_amdgcn_sched_barrier(0);

    mfma_layer(A, Wp2, abase, lane, acc2);
}

// --- pass A: gamma branch; pooled += segment_mean contribution, all in registers.
// Bias gb2 is NOT added here (mean of a constant) — folded into lambda's epilogue. ---
__global__ __launch_bounds__(256, 8) void gamma_kernel(
    const float* __restrict__ x, const int* __restrict__ seg,
    const uint4* __restrict__ Wp1, const float* __restrict__ b1,
    const uint4* __restrict__ Wp2,
    const float* __restrict__ inv_counts, float* __restrict__ pooled, int N)
{
    __shared__ _Float16 A[TILE_R * XSTR];
    __shared__ int segs[TILE_R];
    int tid = threadIdx.x;
    int r0 = blockIdx.x * TILE_R;
    stage_x(A, x, r0, N);
    if (tid < TILE_R) segs[tid] = (r0 + tid < N) ? seg[r0 + tid] : -1;
    __syncthreads();

    int wv = tid >> 6, lane = tid & 63;
    int l15 = lane & 15, q = lane >> 4;
    f32x4 acc2[8];
    mlp_core(A, Wp1, b1, Wp2, wv, lane, acc2);

    // segmented reduction over this wave's 16 rows, in registers:
    // lane holds rows q*4+r of cols nt*16+l15; sum r in-lane, q via shfl_xor(16,32).
    int rb = wv * 16;
    int sF = segs[rb], sL = segs[rb + 15];
    if (sF == sL) {                               // common case: one segment (or all OOB)
        if (sF >= 0) {
            float ic = inv_counts[sF];
            #pragma unroll
            for (int nt = 0; nt < 8; ++nt) {
                float t = (acc2[nt][0] + acc2[nt][1]) + (acc2[nt][2] + acc2[nt][3]);
                t += __shfl_xor(t, 16);
                t += __shfl_xor(t, 32);
                if (q == 0) atomicAdd(&pooled[sF * FW + nt * 16 + l15], t * ic);
            }
        }
    } else {                                      // boundary tile: walk runs (wave-uniform)
        int i = 0;
        while (i < 16) {
            int s = segs[rb + i];
            int e = i + 1;
            while (e < 16 && segs[rb + e] == s) ++e;
            if (s >= 0) {
                float ic = inv_counts[s];
                #pragma unroll
                for (int nt = 0; nt < 8; ++nt) {
                    float t = 0.f;
                    #pragma unroll
                    for (int r = 0; r < 4; ++r) {
                        int lr = q * 4 + r;
                        t += (lr >= i && lr < e) ? acc2[nt][r] : 0.f;
                    }
                    t += __shfl_xor(t, 16);
                    t += __shfl_xor(t, 32);
                    if (q == 0) atomicAdd(&pooled[s * FW + nt * 16 + l15], t * ic);
                }
            }
            i = e;
        }
    }
}

// --- pass B: lambda branch + pooled + (lb2+gb2) + tanh, direct store ---
__global__ __launch_bounds__(256, 8) void lambda_kernel(
    const float* __restrict__ x, const int* __restrict__ seg,
    const uint4* __restrict__ Wp1, const float* __restrict__ b1,
    const uint4* __restrict__ Wp2, const float* __restrict__ lb2,
    const float* __restrict__ gb2,
    const float* __restrict__ pooled, float* __restrict__ out, int N)
{
    __shared__ _Float16 A[TILE_R * XSTR];
    __shared__ int segs[TILE_R];
    int tid = threadIdx.x;
    int r0 = blockIdx.x * TILE_R;
    stage_x(A, x, r0, N);
    if (tid < TILE_R) segs[tid] = (r0 + tid < N) ? seg[r0 + tid] : -1;
    __syncthreads();

    int wv = tid >> 6, lane = tid & 63;
    int l15 = lane & 15, q = lane >> 4;
    f32x4 acc2[8];
    mlp_core(A, Wp1, b1, Wp2, wv, lane, acc2);

    float bias[8];
    #pragma unroll
    for (int nt = 0; nt < 8; ++nt) bias[nt] = lb2[nt * 16 + l15] + gb2[nt * 16 + l15];

    #pragma unroll
    for (int r = 0; r < 4; ++r) {
        int lrow = wv * 16 + q * 4 + r;
        int row = r0 + lrow;
        if (row < N) {
            const float* prow = &pooled[segs[lrow] * FW];
            #pragma unroll
            for (int nt = 0; nt < 8; ++nt) {
                int col = nt * 16 + l15;
                out[(long)row * FW + col] = fast_tanh(acc2[nt][r] + bias[nt] + prow[col]);
            }
        }
    }
}

extern "C" void kernel_launch(void* const* d_in, const int* in_sizes, int n_in,
                              void* d_out, int out_size, void* d_ws, size_t ws_size,
                              hipStream_t stream) {
    const float* x   = (const float*)d_in[0];
    const int*   seg = (const int*)  d_in[1];
    const float* lW1 = (const float*)d_in[2];
    const float* lb1 = (const float*)d_in[3];
    const float* lW2 = (const float*)d_in[4];
    const float* lb2 = (const float*)d_in[5];
    const float* gW1 = (const float*)d_in[6];
    const float* gb1 = (const float*)d_in[7];
    const float* gW2 = (const float*)d_in[8];
    const float* gb2 = (const float*)d_in[9];
    float* out = (float*)d_out;

    const int N = in_sizes[0] / FW;            // 500000

    char* ws = (char*)d_ws;
    float* pooled     = (float*)ws;                         // 256*128*4 = 131072 B
    float* inv_counts = (float*)(ws + 131072);              // 1024 B
    uint4* WpL1 = (uint4*)(ws + 132096);                    // 32 KB each
    uint4* WpL2 = WpL1 + 2048;
    uint4* WpG1 = WpL2 + 2048;
    uint4* WpG2 = WpG1 + 2048;

    prep_kernel<<<5, 256, 0, stream>>>(lW1, lW2, gW1, gW2, WpL1, WpL2, WpG1, WpG2,
                                       seg, inv_counts, pooled, N);

    int nb = (N + TILE_R - 1) / TILE_R;        // 7813
    gamma_kernel<<<nb, 256, 0, stream>>>(x, seg, WpG1, gb1, WpG2, inv_counts, pooled, N);
    lambda_kernel<<<nb, 256, 0, stream>>>(x, seg, WpL1, lb1, WpL2, lb2, gb2, pooled, out, N);
}